// Round 7
// baseline (403.450 us; speedup 1.0000x reference)
//
#include <hip/hip_runtime.h>

#define TLEN  4096
#define NROWS 4096
#define RPB   32            // rows per block (owned by the scan wave)
#define K     32            // timesteps per chunk
#define NC    (TLEN / K)    // 128 chunks
#define IBSL  (8 * 64)      // raw-input slot: 8 DMA batches x 64 lanes (float4 units) = 8 KB
#define SGSL  (16 * 64)     // coef slot: 16 tp-granules x 64 lanes (float4 units)
#define STP   34            // staging pitch (dwords): 32 steps + 2 pad (b64-aligned, conflict-free phases)
#define STSL  (64 * STP)    // output-staging slot (floats)
#define UN    8             // exact-path unroll

__device__ __forceinline__ float fexp2(float x) { return __builtin_amdgcn_exp2f(x); }
__device__ __forceinline__ float frcp(float x)  { return __builtin_amdgcn_rcpf(x); }
__device__ __forceinline__ float sigz(float z)  { return frcp(1.0f + fexp2(z)); }

// Swap adjacent lanes (lane ^ 1): DPP quad_perm [1,0,3,2].
__device__ __forceinline__ float lane_swap1(float v) {
    int r = __builtin_amdgcn_update_dpp(0, __float_as_int(v), 0xB1, 0xF, 0xF, true);
    return __int_as_float(r);
}

// Async global->LDS DMA, 16 B per lane, no VGPR destination (fire-and-forget).
__device__ __forceinline__ void gload_lds16(const float4* g, float4* l) {
    __builtin_amdgcn_global_load_lds((const __attribute__((address_space(1))) void*)g,
                                     (__attribute__((address_space(3))) void*)l,
                                     16, 0, 0);
}
__device__ __forceinline__ void fence_vm0() {
    __builtin_amdgcn_s_waitcnt(0x0f70);   // vmcnt(0); lgkmcnt/expcnt unconstrained
    __builtin_amdgcn_sched_barrier(0);
}

// ---------------------------------------------------------------------------
// Round-7. r6 post-mortem: wall = max(scan, helper) per chunk; r6's produce
// wave was HBM-latency-bound (VGPR-limited load pipeline, ~4100 cyc/chunk >
// scan's ~2400). Fix: helper's inputs arrive via global_load_lds DMA with
// 2-chunk kick-ahead (zero register-exposed latency, r0-proven), helper
// computes coefs from LDS and flushes outputs. Scan wave is BYTE-IDENTICAL
// to r6's verified scan (~10.7 slots/step).
//
//   wave 0 (scan): per step-pair: 2x{m=fma(a,x,b); t1v; t2v; b2; DPP; dx;
//     x+=dx; dz; sig=fma(u,dz,sig)} + u-refresh + ds_write_b64 + ds_read_b128.
//     Deg-1 sigma-Taylor, exact resync every 16 steps.
//   wave 1 (helper), per chunk c: fence(DMA c+1, kicked 1 iter ago) ->
//     produce coefs(c+1) from ibuf -> kick DMA(c+2) -> flush st(c-1).
//     ~330 slots/chunk, no latency cliffs -> stays under scan's ~2400 cyc.
// ---------------------------------------------------------------------------
__device__ void run_fast(const float* __restrict__ inp, const float* __restrict__ prm,
                         float* __restrict__ out,
                         float4* __restrict__ ibuf,   // [2][8 batch][64 lane] raw inputs
                         float4* __restrict__ sgbuf,  // [2][16 tp][64 lane] coef pairs
                         float*  __restrict__ st) {   // [2][64 lane][STP]
    const int tid  = threadIdx.x;
    const int wid  = tid >> 6;          // 0 = scan, 1 = helper
    const int lane = tid & 63;
    const int R0   = blockIdx.x * RPB;
    const float L2E = 1.4426950408889634f;
    float2* __restrict__ out2 = (float2*)out;

    if (wid == 1) {
        // ---------------- helper wave ----------------
        const int row = lane >> 1, dir = lane & 1;   // dir 0 = x ('ax'), 1 = y ('by')
        const float sd = dir ? prm[8] : prm[4];
        const float mn = dir ? prm[7] : prm[3];
        const float c1 = -sd * L2E, c0 = sd * mn * L2E;
        const float gA = dir ? (prm[6] / prm[1]) : (prm[2] / prm[0]);
        const float P  = gA * (dir ? prm[9] : prm[5]);
        const float Gn = -gA;

        // DMA source (r0 pattern): lane l covers row (l&31), granule-half l>>5.
        const float4* gbase = (const float4*)inp
                            + (size_t)(R0 + (lane & 31)) * (TLEN / 2) + (lane >> 5);
        auto kick = [&](int c) {   // raw chunk c -> ibuf slot c&1; LDS[j*64+lane]
            float4* lb = ibuf + ((c & 1) ? IBSL : 0);
            const float4* gp = gbase + c * 16;
#pragma unroll
            for (int j = 0; j < 8; ++j)
                gload_lds16(gp + 2 * j, lb + (j << 6));
        };
        auto produce = [&](int c) {   // coef pairs of chunk c -> sgbuf slot c&1
            const float4* ib = ibuf + ((c & 1) ? IBSL : 0);
            float4* sl = sgbuf + ((c & 1) ? SGSL : 0);
#pragma unroll
            for (int g = 0; g < 16; ++g) {
                // granule g of row r sits at ibuf[(g>>1)*64 + (g&1)*32 + r]
                float4 v = ib[(g >> 1) * 64 + (g & 1) * 32 + row];  // pair-broadcast
                float p0 = dir ? v.y : v.x;
                float p1 = dir ? v.w : v.z;
                float s0 = sigz(__builtin_fmaf(c1, p0, c0));
                float s1 = sigz(__builtin_fmaf(c1, p1, c0));
                float4 o; o.x = Gn * s0; o.y = P * s0;
                          o.z = Gn * s1; o.w = P * s1;
                sl[g * 64 + lane] = o;               // consecutive lanes: conflict-free
            }
        };
        auto flush = [&](int c) {     // st slot c&1 -> out, 256B coalesced runs
            const float* sl = st + ((c & 1) ? STSL : 0);
            const int col = lane & 31;
#pragma unroll
            for (int j = 0; j < 16; ++j) {
                int ro = 2 * j + (lane >> 5);
                float2 v;
                v.x = sl[(2 * ro)     * STP + col];  // x of row ro, step col
                v.y = sl[(2 * ro + 1) * STP + col];  // y of row ro, step col
                out2[(size_t)(R0 + ro) * TLEN + (size_t)c * K + col] = v;
            }
        };

        kick(0);
        fence_vm0();                  // chunk 0 raw ready (one-time latency hit)
        produce(0);
        kick(1);
        __syncthreads();              // coefs chunk 0 ready for scan
        for (int c = 0; c < NC; ++c) {
            if (c + 1 < NC) {
                fence_vm0();          // DMA(c+1) kicked one full iteration ago
                produce(c + 1);
            }
            if (c + 2 < NC) kick(c + 2);
            if (c >= 1)     flush(c - 1);
            __syncthreads();
        }
        flush(NC - 1);                // epilogue: last chunk's outputs
    } else {
        // ---------------- scan wave (byte-identical to r6's verified scan) ----
        // Lane pair (2r, 2r+1) owns row r: even lane = x, odd = y.
        const int par = lane & 1;
        const int sfB = par ? 22 : 18, t2B = par ? 10 : 14;
        const float ic  = 1.0f / prm[par];
        const float g1  = prm[sfB] * ic, P1 = g1 * prm[sfB + 3], Gn1 = -g1; // self
        const float g2  = prm[t2B] * ic, P2 = g2 * prm[t2B + 3], Gn2 = -g2; // cross
        const float sdz = prm[sfB + 2];
        const float c1s = -sdz * L2E, c0s = sdz * prm[sfB + 1] * L2E;

        float x   = par ? 1.0f : 0.0f;
        float sig = sigz(__builtin_fmaf(c1s, x, c0s));
        float u   = __builtin_fmaf(-sig, sig, sig);   // sig*(1-sig)

        auto resync = [&]() {                         // exact sigma (off-chain cost)
            sig = sigz(__builtin_fmaf(c1s, x, c0s));
            u   = __builtin_fmaf(-sig, sig, sig);
        };

        __syncthreads();                       // sgbuf slot 0 ready
        for (int c = 0; c < NC; ++c) {
            const float4* lb = sgbuf + ((c & 1) ? SGSL : 0);
            float* wp = st + ((c & 1) ? STSL : 0) + lane * STP;
            float4 f0 = lb[lane];
            float4 f1 = lb[64 + lane];
#pragma unroll
            for (int tp = 0; tp < 16; ++tp) {
                float4 f = f0; f0 = f1;
                if (tp < 14) f1 = lb[(tp + 2) * 64 + lane];   // 2-granule lookahead
                // step A (coefs f.x=Gn*sgin, f.y=P*sgin premade by helper)
                float m   = __builtin_fmaf(f.x, x, f.y);
                float t1v = __builtin_fmaf(Gn1, x, P1);
                float t2v = __builtin_fmaf(Gn2, x, P2);
                float b2  = __builtin_fmaf(sig, t1v, m);
                float sc  = lane_swap1(sig);
                float dxa = __builtin_fmaf(sc, t2v, b2);
                x = x + dxa;
                float xa  = x;
                float dza = sdz * dxa;
                sig = __builtin_fmaf(u, dza, sig);            // deg-1 Taylor
                // step B
                float m2   = __builtin_fmaf(f.z, x, f.w);
                float t1v2 = __builtin_fmaf(Gn1, x, P1);
                float t2v2 = __builtin_fmaf(Gn2, x, P2);
                float b22  = __builtin_fmaf(sig, t1v2, m2);
                float sc2  = lane_swap1(sig);
                float dxb  = __builtin_fmaf(sc2, t2v2, b22);
                x = x + dxb;
                float dzb = sdz * dxb;
                sig = __builtin_fmaf(u, dzb, sig);            // deg-1 Taylor
                u   = __builtin_fmaf(-sig, sig, sig);         // refresh once / pair
                float2 w2; w2.x = xa; w2.y = x;
                *(float2*)(wp + 2 * tp) = w2;                 // ds_write_b64
                if (tp == 7) resync();                        // mid-chunk resync
            }
            resync();                                         // end-chunk resync
            __syncthreads();                   // hand slots to helper / get next
        }
    }
}

// ---------------------------------------------------------------------------
// Exact fallback for non-shared params (proven path; 128-thr blocks cover
// all 8192 lanes, excess threads idle).
// ---------------------------------------------------------------------------
struct LaneConst {
    float c1_in, c0_in, c1_sf, c0_sf, c1_ot, c0_ot;
    float gS_in, gS_cr, gS_sf, gP_in, gP_cr, gP_sf;
};

__device__ __forceinline__ float do_step_exact(float s, float pre_in, const LaneConst& k) {
    float sig_in = sigz(__builtin_fmaf(k.c1_in, pre_in, k.c0_in));
    float sig_sf = sigz(__builtin_fmaf(k.c1_sf, s, k.c0_sf));
    float sig_ot = sigz(__builtin_fmaf(k.c1_ot, s, k.c0_ot));
    float sig_cr = lane_swap1(sig_ot);
    float S = __builtin_fmaf(k.gS_in, sig_in, __builtin_fmaf(k.gS_cr, sig_cr, k.gS_sf * sig_sf));
    float P = __builtin_fmaf(k.gP_in, sig_in, __builtin_fmaf(k.gP_cr, sig_cr, k.gP_sf * sig_sf));
    return s + __builtin_fmaf(S, -s, P);
}

__device__ void run_exact(const float* __restrict__ inp, const float* __restrict__ prm,
                          float* __restrict__ out) {
    const int tid = blockIdx.x * 128 + threadIdx.x;
    const int row = tid >> 1;
    if (row >= NROWS) return;
    const int par = tid & 1;
    const float L2E = 1.4426950408889634f;
    const int inB = par ? 6 : 2, sfB = par ? 22 : 18, otB = par ? 14 : 10, crB = par ? 10 : 14;
    const float invc = 1.0f / prm[par];
    LaneConst k;
    float sd = prm[inB + 2], mn = prm[inB + 1];
    k.c1_in = -sd * L2E; k.c0_in = sd * mn * L2E;
    sd = prm[sfB + 2]; mn = prm[sfB + 1];
    k.c1_sf = -sd * L2E; k.c0_sf = sd * mn * L2E;
    sd = prm[otB + 2]; mn = prm[otB + 1];
    k.c1_ot = -sd * L2E; k.c0_ot = sd * mn * L2E;
    k.gS_in = prm[inB] * invc; k.gP_in = k.gS_in * prm[inB + 3];
    k.gS_sf = prm[sfB] * invc; k.gP_sf = k.gS_sf * prm[sfB + 3];
    k.gS_cr = prm[crB] * invc; k.gP_cr = k.gS_cr * prm[crB + 3];

    const float4* __restrict__ src = (const float4*)inp + (size_t)row * (TLEN / 2);
    float* __restrict__ dst = out + (size_t)row * (TLEN * 2) + par;
    float s = par ? 1.0f : 0.0f;

    float4 cur[UN], nxt[UN];
#pragma unroll
    for (int j = 0; j < UN; ++j) cur[j] = src[j];
    const int NIT = TLEN / (2 * UN);
    for (int it = 0; it < NIT; ++it) {
        if (it + 1 < NIT) {
#pragma unroll
            for (int j = 0; j < UN; ++j) nxt[j] = src[(it + 1) * UN + j];
        }
        float* dptr = dst + it * (UN * 4);
#pragma unroll
        for (int j = 0; j < UN; ++j) {
            float4 f = cur[j];
            s = do_step_exact(s, par ? f.y : f.x, k);
            dptr[j * 4] = s;
            s = do_step_exact(s, par ? f.w : f.z, k);
            dptr[j * 4 + 2] = s;
        }
#pragma unroll
        for (int j = 0; j < UN; ++j) cur[j] = nxt[j];
    }
}

__global__ __launch_bounds__(128, 1)
void memcell_scan(const float* __restrict__ inp, const float* __restrict__ prm,
                  float* __restrict__ out) {
    __shared__ float4 ibuf[2 * IBSL];    // 16 KB raw-input DMA double-buffer
    __shared__ float4 sgbuf[2 * SGSL];   // 32 KB coef double-buffer
    __shared__ float  st[2 * STSL];      // 17.4 KB output staging double-buffer

    // Fast-path guard:
    //  - shared (mean,std) between self & cross state dirs (xx==xy, yy==yx)
    //  - g >= 0, caps > 0        -> states stay in hull{s0, pots}
    //  - sum(g/cap) <= 0.25      -> no overshoot
    //  - wb = std*max|dx| <= 0.02 -> deg-1 sigma-Taylor valid
    //    (exact resync every 16 steps bounds drift to ~1e-4)
    //  - |z| <= 20               -> sigz well-conditioned
    const bool shared = (prm[11] == prm[19]) && (prm[12] == prm[20]) &&
                        (prm[15] == prm[23]) && (prm[16] == prm[24]);
    const float capx = prm[0], capy = prm[1];
    const bool gpos = prm[2] >= 0.f && prm[6] >= 0.f && prm[10] >= 0.f &&
                      prm[14] >= 0.f && prm[18] >= 0.f && prm[22] >= 0.f &&
                      capx > 0.f && capy > 0.f;
    const float sx = (prm[2] + prm[14] + prm[18]) / capx;
    const float sy = (prm[6] + prm[10] + prm[22]) / capy;
    const float lox = fminf(0.f, fminf(prm[5], fminf(prm[17], prm[21])));
    const float hix = fmaxf(0.f, fmaxf(prm[5], fmaxf(prm[17], prm[21])));
    const float loy = fminf(1.f, fminf(prm[9], fminf(prm[13], prm[25])));
    const float hiy = fmaxf(1.f, fmaxf(prm[9], fmaxf(prm[13], prm[25])));
    const float wbx = prm[20] * sx * (hix - lox), wby = prm[24] * sy * (hiy - loy);
    const float zmx = prm[20] * fmaxf(fabsf(lox - prm[19]), fabsf(hix - prm[19]));
    const float zmy = prm[24] * fmaxf(fabsf(loy - prm[23]), fabsf(hiy - prm[23]));
    const bool fast = shared && gpos && sx <= 0.25f && sy <= 0.25f &&
                      wbx <= 0.02f && wby <= 0.02f && zmx <= 20.f && zmy <= 20.f;
    if (fast) {
        run_fast(inp, prm, out, ibuf, sgbuf, st);
    } else {
        run_exact(inp, prm, out);
    }
}

extern "C" void kernel_launch(void* const* d_in, const int* in_sizes, int n_in,
                              void* d_out, int out_size, void* d_ws, size_t ws_size,
                              hipStream_t stream) {
    (void)in_sizes; (void)n_in; (void)d_ws; (void)ws_size; (void)out_size;
    const float* inp = (const float*)d_in[0];
    const float* prm = (const float*)d_in[1];
    float* out = (float*)d_out;
    memcell_scan<<<dim3(NROWS / RPB), dim3(128), 0, stream>>>(inp, prm, out);
}

// Round 8
// 388.469 us; speedup vs baseline: 1.0386x; 1.0386x over previous
//
#include <hip/hip_runtime.h>

#define TLEN  4096
#define NROWS 4096
#define RPB   32            // rows per block (owned by the scan wave)
#define K     32            // timesteps per chunk
#define NC    (TLEN / K)    // 128 chunks
#define IBSL  (8 * 64)      // raw-input slot: 8 DMA batches x 64 lanes (float4 units) = 8 KB
#define SGSL  (16 * 64)     // coef slot: 16 tp-granules x 64 lanes (float4 units)
#define STP   34            // staging pitch (dwords): 32 steps + 2 pad
#define STSL  (64 * STP)    // output-staging slot (floats)
#define UN    8             // exact-path unroll

__device__ __forceinline__ float fexp2(float x) { return __builtin_amdgcn_exp2f(x); }
__device__ __forceinline__ float frcp(float x)  { return __builtin_amdgcn_rcpf(x); }
__device__ __forceinline__ float sigz(float z)  { return frcp(1.0f + fexp2(z)); }

// Swap adjacent lanes (lane ^ 1): DPP quad_perm [1,0,3,2].
__device__ __forceinline__ float lane_swap1(float v) {
    int r = __builtin_amdgcn_update_dpp(0, __float_as_int(v), 0xB1, 0xF, 0xF, true);
    return __int_as_float(r);
}

// Async global->LDS DMA, 16 B per lane, no VGPR destination (fire-and-forget).
__device__ __forceinline__ void gload_lds16(const float4* g, float4* l) {
    __builtin_amdgcn_global_load_lds((const __attribute__((address_space(1))) void*)g,
                                     (__attribute__((address_space(3))) void*)l,
                                     16, 0, 0);
}
// waitcnt imm encoding (gfx9): vmcnt[3:0]=bits3:0, expcnt=bits6:4,
// lgkmcnt=bits11:8, vmcnt[5:4]=bits15:14.
__device__ __forceinline__ void fence_vm0() {     // vmcnt(0), rest unconstrained
    __builtin_amdgcn_s_waitcnt(0x0f70);
    __builtin_amdgcn_sched_barrier(0);
}
__device__ __forceinline__ void fence_vm16() {    // vmcnt(16): retire all but 16 newest
    __builtin_amdgcn_s_waitcnt(0x4f70);
    __builtin_amdgcn_sched_barrier(0);
}
// Helper-side barrier: make this wave's LDS writes visible (lgkmcnt(0)) and
// rendezvous -- WITHOUT draining vmcnt. DMA loads + flush stores stay in
// flight across the barrier (this is the entire point of round 8: the
// __syncthreads it replaces drains vmcnt(0) every chunk, serializing all
// helper-side global traffic against the barrier).
__device__ __forceinline__ void lds_release_barrier() {
    __builtin_amdgcn_sched_barrier(0);
    __builtin_amdgcn_s_waitcnt(0xc07f);   // lgkmcnt(0); vmcnt/expcnt unconstrained
    __builtin_amdgcn_s_barrier();
    __builtin_amdgcn_sched_barrier(0);
}

// ---------------------------------------------------------------------------
// Round-8. r7 post-mortem: helper's __syncthreads() compiles to
// s_waitcnt vmcnt(0) + s_barrier -> every chunk drained the just-kicked DMA
// (~500-900 cyc exposed) and the flush stores. Fix: helper uses raw s_barrier
// + lgkmcnt(0) only; DMA consumption via counted vmcnt(16) (loads are the
// 8 oldest outstanding ops; the 16 newer flush stores may float). Scan wave
// keeps __syncthreads() -- it has zero VMEM ops, so its drain is free.
// All compute (scan / produce / flush / kick) byte-identical to r7 (passed).
// ---------------------------------------------------------------------------
__device__ void run_fast(const float* __restrict__ inp, const float* __restrict__ prm,
                         float* __restrict__ out,
                         float4* __restrict__ ibuf,   // [2][8 batch][64 lane] raw inputs
                         float4* __restrict__ sgbuf,  // [2][16 tp][64 lane] coef pairs
                         float*  __restrict__ st) {   // [2][64 lane][STP]
    const int tid  = threadIdx.x;
    const int wid  = tid >> 6;          // 0 = scan, 1 = helper
    const int lane = tid & 63;
    const int R0   = blockIdx.x * RPB;
    const float L2E = 1.4426950408889634f;
    float2* __restrict__ out2 = (float2*)out;

    if (wid == 1) {
        // ---------------- helper wave ----------------
        const int row = lane >> 1, dir = lane & 1;   // dir 0 = x ('ax'), 1 = y ('by')
        const float sd = dir ? prm[8] : prm[4];
        const float mn = dir ? prm[7] : prm[3];
        const float c1 = -sd * L2E, c0 = sd * mn * L2E;
        const float gA = dir ? (prm[6] / prm[1]) : (prm[2] / prm[0]);
        const float P  = gA * (dir ? prm[9] : prm[5]);
        const float Gn = -gA;

        // DMA source (r0 pattern): lane l covers row (l&31), granule-half l>>5.
        const float4* gbase = (const float4*)inp
                            + (size_t)(R0 + (lane & 31)) * (TLEN / 2) + (lane >> 5);
        auto kick = [&](int c) {   // raw chunk c -> ibuf slot c&1; LDS[j*64+lane]
            float4* lb = ibuf + ((c & 1) ? IBSL : 0);
            const float4* gp = gbase + c * 16;
#pragma unroll
            for (int j = 0; j < 8; ++j)
                gload_lds16(gp + 2 * j, lb + (j << 6));
        };
        auto produce = [&](int c) {   // coef pairs of chunk c -> sgbuf slot c&1
            const float4* ib = ibuf + ((c & 1) ? IBSL : 0);
            float4* sl = sgbuf + ((c & 1) ? SGSL : 0);
#pragma unroll
            for (int g = 0; g < 16; ++g) {
                // granule g of row r sits at ibuf[(g>>1)*64 + (g&1)*32 + r]
                float4 v = ib[(g >> 1) * 64 + (g & 1) * 32 + row];  // pair-broadcast
                float p0 = dir ? v.y : v.x;
                float p1 = dir ? v.w : v.z;
                float s0 = sigz(__builtin_fmaf(c1, p0, c0));
                float s1 = sigz(__builtin_fmaf(c1, p1, c0));
                float4 o; o.x = Gn * s0; o.y = P * s0;
                          o.z = Gn * s1; o.w = P * s1;
                sl[g * 64 + lane] = o;               // consecutive lanes: conflict-free
            }
        };
        auto flush = [&](int c) {     // st slot c&1 -> out, 256B coalesced runs
            const float* sl = st + ((c & 1) ? STSL : 0);
            const int col = lane & 31;
#pragma unroll
            for (int j = 0; j < 16; ++j) {
                int ro = 2 * j + (lane >> 5);
                float2 v;
                v.x = sl[(2 * ro)     * STP + col];  // x of row ro, step col
                v.y = sl[(2 * ro + 1) * STP + col];  // y of row ro, step col
                out2[(size_t)(R0 + ro) * TLEN + (size_t)c * K + col] = v;
            }
        };

        kick(0);
        fence_vm0();                  // chunk 0 raw ready (one-time latency hit)
        produce(0);
        kick(1);
        lds_release_barrier();        // coefs chunk 0 visible; DMA(1) stays in flight
        for (int c = 0; c < NC; ++c) {
            if (c + 1 < NC) {
                // steady state (c>=2): outstanding = 8 DMA loads (oldest) +
                // 16 flush stores (newest) -> vmcnt(16) retires exactly the
                // loads, issued a full chunk ago => typically zero wait.
                // c<2: no stores in flight yet, count differs -> vmcnt(0).
                if (c < 2) fence_vm0(); else fence_vm16();
                produce(c + 1);
            }
            if (c + 2 < NC) kick(c + 2);
            if (c >= 1)     flush(c - 1);
            lds_release_barrier();
        }
        flush(NC - 1);                // epilogue: last chunk's outputs
    } else {
        // ---------------- scan wave (byte-identical to r6/r7 verified scan) --
        // Lane pair (2r, 2r+1) owns row r: even lane = x, odd = y.
        const int par = lane & 1;
        const int sfB = par ? 22 : 18, t2B = par ? 10 : 14;
        const float ic  = 1.0f / prm[par];
        const float g1  = prm[sfB] * ic, P1 = g1 * prm[sfB + 3], Gn1 = -g1; // self
        const float g2  = prm[t2B] * ic, P2 = g2 * prm[t2B + 3], Gn2 = -g2; // cross
        const float sdz = prm[sfB + 2];
        const float c1s = -sdz * L2E, c0s = sdz * prm[sfB + 1] * L2E;

        float x   = par ? 1.0f : 0.0f;
        float sig = sigz(__builtin_fmaf(c1s, x, c0s));
        float u   = __builtin_fmaf(-sig, sig, sig);   // sig*(1-sig)

        auto resync = [&]() {                         // exact sigma (off-chain cost)
            sig = sigz(__builtin_fmaf(c1s, x, c0s));
            u   = __builtin_fmaf(-sig, sig, sig);
        };

        __syncthreads();                       // sgbuf slot 0 ready (scan has no
                                               // VMEM -> its vmcnt drain is free)
        for (int c = 0; c < NC; ++c) {
            const float4* lb = sgbuf + ((c & 1) ? SGSL : 0);
            float* wp = st + ((c & 1) ? STSL : 0) + lane * STP;
            float4 f0 = lb[lane];
            float4 f1 = lb[64 + lane];
#pragma unroll
            for (int tp = 0; tp < 16; ++tp) {
                float4 f = f0; f0 = f1;
                if (tp < 14) f1 = lb[(tp + 2) * 64 + lane];   // 2-granule lookahead
                // step A (coefs f.x=Gn*sgin, f.y=P*sgin premade by helper)
                float m   = __builtin_fmaf(f.x, x, f.y);
                float t1v = __builtin_fmaf(Gn1, x, P1);
                float t2v = __builtin_fmaf(Gn2, x, P2);
                float b2  = __builtin_fmaf(sig, t1v, m);
                float sc  = lane_swap1(sig);
                float dxa = __builtin_fmaf(sc, t2v, b2);
                x = x + dxa;
                float xa  = x;
                float dza = sdz * dxa;
                sig = __builtin_fmaf(u, dza, sig);            // deg-1 Taylor
                // step B
                float m2   = __builtin_fmaf(f.z, x, f.w);
                float t1v2 = __builtin_fmaf(Gn1, x, P1);
                float t2v2 = __builtin_fmaf(Gn2, x, P2);
                float b22  = __builtin_fmaf(sig, t1v2, m2);
                float sc2  = lane_swap1(sig);
                float dxb  = __builtin_fmaf(sc2, t2v2, b22);
                x = x + dxb;
                float dzb = sdz * dxb;
                sig = __builtin_fmaf(u, dzb, sig);            // deg-1 Taylor
                u   = __builtin_fmaf(-sig, sig, sig);         // refresh once / pair
                float2 w2; w2.x = xa; w2.y = x;
                *(float2*)(wp + 2 * tp) = w2;                 // ds_write_b64
                if (tp == 7) resync();                        // mid-chunk resync
            }
            resync();                                         // end-chunk resync
            __syncthreads();                   // hand slots to helper / get next
        }
    }
}

// ---------------------------------------------------------------------------
// Exact fallback for non-shared params (proven path; 128-thr blocks cover
// all 8192 lanes, excess threads idle).
// ---------------------------------------------------------------------------
struct LaneConst {
    float c1_in, c0_in, c1_sf, c0_sf, c1_ot, c0_ot;
    float gS_in, gS_cr, gS_sf, gP_in, gP_cr, gP_sf;
};

__device__ __forceinline__ float do_step_exact(float s, float pre_in, const LaneConst& k) {
    float sig_in = sigz(__builtin_fmaf(k.c1_in, pre_in, k.c0_in));
    float sig_sf = sigz(__builtin_fmaf(k.c1_sf, s, k.c0_sf));
    float sig_ot = sigz(__builtin_fmaf(k.c1_ot, s, k.c0_ot));
    float sig_cr = lane_swap1(sig_ot);
    float S = __builtin_fmaf(k.gS_in, sig_in, __builtin_fmaf(k.gS_cr, sig_cr, k.gS_sf * sig_sf));
    float P = __builtin_fmaf(k.gP_in, sig_in, __builtin_fmaf(k.gP_cr, sig_cr, k.gP_sf * sig_sf));
    return s + __builtin_fmaf(S, -s, P);
}

__device__ void run_exact(const float* __restrict__ inp, const float* __restrict__ prm,
                          float* __restrict__ out) {
    const int tid = blockIdx.x * 128 + threadIdx.x;
    const int row = tid >> 1;
    if (row >= NROWS) return;
    const int par = tid & 1;
    const float L2E = 1.4426950408889634f;
    const int inB = par ? 6 : 2, sfB = par ? 22 : 18, otB = par ? 14 : 10, crB = par ? 10 : 14;
    const float invc = 1.0f / prm[par];
    LaneConst k;
    float sd = prm[inB + 2], mn = prm[inB + 1];
    k.c1_in = -sd * L2E; k.c0_in = sd * mn * L2E;
    sd = prm[sfB + 2]; mn = prm[sfB + 1];
    k.c1_sf = -sd * L2E; k.c0_sf = sd * mn * L2E;
    sd = prm[otB + 2]; mn = prm[otB + 1];
    k.c1_ot = -sd * L2E; k.c0_ot = sd * mn * L2E;
    k.gS_in = prm[inB] * invc; k.gP_in = k.gS_in * prm[inB + 3];
    k.gS_sf = prm[sfB] * invc; k.gP_sf = k.gS_sf * prm[sfB + 3];
    k.gS_cr = prm[crB] * invc; k.gP_cr = k.gS_cr * prm[crB + 3];

    const float4* __restrict__ src = (const float4*)inp + (size_t)row * (TLEN / 2);
    float* __restrict__ dst = out + (size_t)row * (TLEN * 2) + par;
    float s = par ? 1.0f : 0.0f;

    float4 cur[UN], nxt[UN];
#pragma unroll
    for (int j = 0; j < UN; ++j) cur[j] = src[j];
    const int NIT = TLEN / (2 * UN);
    for (int it = 0; it < NIT; ++it) {
        if (it + 1 < NIT) {
#pragma unroll
            for (int j = 0; j < UN; ++j) nxt[j] = src[(it + 1) * UN + j];
        }
        float* dptr = dst + it * (UN * 4);
#pragma unroll
        for (int j = 0; j < UN; ++j) {
            float4 f = cur[j];
            s = do_step_exact(s, par ? f.y : f.x, k);
            dptr[j * 4] = s;
            s = do_step_exact(s, par ? f.w : f.z, k);
            dptr[j * 4 + 2] = s;
        }
#pragma unroll
        for (int j = 0; j < UN; ++j) cur[j] = nxt[j];
    }
}

__global__ __launch_bounds__(128, 1)
void memcell_scan(const float* __restrict__ inp, const float* __restrict__ prm,
                  float* __restrict__ out) {
    __shared__ float4 ibuf[2 * IBSL];    // 16 KB raw-input DMA double-buffer
    __shared__ float4 sgbuf[2 * SGSL];   // 32 KB coef double-buffer
    __shared__ float  st[2 * STSL];      // 17.4 KB output staging double-buffer

    // Fast-path guard:
    //  - shared (mean,std) between self & cross state dirs (xx==xy, yy==yx)
    //  - g >= 0, caps > 0        -> states stay in hull{s0, pots}
    //  - sum(g/cap) <= 0.25      -> no overshoot
    //  - wb = std*max|dx| <= 0.02 -> deg-1 sigma-Taylor valid
    //    (exact resync every 16 steps bounds drift to ~1e-4)
    //  - |z| <= 20               -> sigz well-conditioned
    const bool shared = (prm[11] == prm[19]) && (prm[12] == prm[20]) &&
                        (prm[15] == prm[23]) && (prm[16] == prm[24]);
    const float capx = prm[0], capy = prm[1];
    const bool gpos = prm[2] >= 0.f && prm[6] >= 0.f && prm[10] >= 0.f &&
                      prm[14] >= 0.f && prm[18] >= 0.f && prm[22] >= 0.f &&
                      capx > 0.f && capy > 0.f;
    const float sx = (prm[2] + prm[14] + prm[18]) / capx;
    const float sy = (prm[6] + prm[10] + prm[22]) / capy;
    const float lox = fminf(0.f, fminf(prm[5], fminf(prm[17], prm[21])));
    const float hix = fmaxf(0.f, fmaxf(prm[5], fmaxf(prm[17], prm[21])));
    const float loy = fminf(1.f, fminf(prm[9], fminf(prm[13], prm[25])));
    const float hiy = fmaxf(1.f, fmaxf(prm[9], fmaxf(prm[13], prm[25])));
    const float wbx = prm[20] * sx * (hix - lox), wby = prm[24] * sy * (hiy - loy);
    const float zmx = prm[20] * fmaxf(fabsf(lox - prm[19]), fabsf(hix - prm[19]));
    const float zmy = prm[24] * fmaxf(fabsf(loy - prm[23]), fabsf(hiy - prm[23]));
    const bool fast = shared && gpos && sx <= 0.25f && sy <= 0.25f &&
                      wbx <= 0.02f && wby <= 0.02f && zmx <= 20.f && zmy <= 20.f;
    if (fast) {
        run_fast(inp, prm, out, ibuf, sgbuf, st);
    } else {
        run_exact(inp, prm, out);
    }
}

extern "C" void kernel_launch(void* const* d_in, const int* in_sizes, int n_in,
                              void* d_out, int out_size, void* d_ws, size_t ws_size,
                              hipStream_t stream) {
    (void)in_sizes; (void)n_in; (void)d_ws; (void)ws_size; (void)out_size;
    const float* inp = (const float*)d_in[0];
    const float* prm = (const float*)d_in[1];
    float* out = (float*)d_out;
    memcell_scan<<<dim3(NROWS / RPB), dim3(128), 0, stream>>>(inp, prm, out);
}

// Round 9
// 341.337 us; speedup vs baseline: 1.1820x; 1.1381x over previous
//
#include <hip/hip_runtime.h>

#define TLEN  4096
#define NROWS 4096
#define RPB   32            // rows per block (owned by the scan wave)
#define K     32            // timesteps per chunk
#define NC    (TLEN / K)    // 128 chunks
#define LDPAD 66            // staged-output row pitch (dwords): 64 data + 2 pad
#define SGSL  (16 * 32)     // sgin slot: 16 tp-granules x 32 rows (float4 units)
#define STSL  (RPB * LDPAD) // output-staging slot (floats)
#define UN    8             // exact-path unroll

__device__ __forceinline__ float fexp2(float x) { return __builtin_amdgcn_exp2f(x); }
__device__ __forceinline__ float frcp(float x)  { return __builtin_amdgcn_rcpf(x); }
__device__ __forceinline__ float sigz(float z)  { return frcp(1.0f + fexp2(z)); }

// Swap adjacent lanes (lane ^ 1): DPP quad_perm [1,0,3,2].
__device__ __forceinline__ float lane_swap1(float v) {
    int r = __builtin_amdgcn_update_dpp(0, __float_as_int(v), 0xB1, 0xF, 0xF, true);
    return __int_as_float(r);
}

// ---------------------------------------------------------------------------
// Round-9 = round-3 structure (best measured: 196.9us, helper fully hidden,
// 0 conflicts) + exactly two proven deltas:
//   (1) scan sigma update deg-2 -> deg-1 Taylor (-3 slots/step), exact resync
//       every 16 steps, wb-guard tightened to 0.02 (r8 validated this exact
//       numeric scheme: absmax unchanged at 0.00390625).
//   (2) helper register double-buffer (bufA/bufB): chunk c+2's inputs load
//       while chunk c+1's sigmoids are produced -> HBM latency rides the
//       barrier wait, not the helper's compute (r0-proven pattern).
// Everything else -- layouts, flush, barriers, produce math -- is r3 verbatim.
// Lesson from r4-r8: pipeline restructurings (wave splits, DMA staging, raw
// barriers) break the r3 overlap in unmodeled ways; only scan-stream length
// has a cost model that has never failed.
// ---------------------------------------------------------------------------
__device__ void run_fast(const float* __restrict__ inp, const float* __restrict__ prm,
                         float* __restrict__ out,
                         float4* __restrict__ sgbuf,  // [2][16 tp][32 row] float4
                         float*  __restrict__ st) {   // [2][RPB][LDPAD]
    const int tid  = threadIdx.x;
    const int wid  = tid >> 6;          // 0 = scan wave, 1 = helper wave
    const int lane = tid & 63;
    const int R0   = blockIdx.x * RPB;
    const float L2E = 1.4426950408889634f;
    float2* __restrict__ out2 = (float2*)out;

    if (wid == 1) {
        // ---------------- helper wave ----------------
        const int r = lane & 31, h = lane >> 5;
        // input-sigmoid constants: 'ax' dir for x (base 2), 'by' dir for y (base 6)
        const float c1x = -prm[4] * L2E, c0x = prm[4] * prm[3] * L2E;
        const float c1y = -prm[8] * L2E, c0y = prm[8] * prm[7] * L2E;
        const float4* __restrict__ src = (const float4*)inp + (size_t)(R0 + r) * (TLEN / 2);

        float4 bufA[8], bufB[8];

        auto produce_reg = [&](const float4* buf, int c) {  // regs -> sgbuf slot c&1
            float4* sl = sgbuf + ((c & 1) ? SGSL : 0);
#pragma unroll
            for (int j = 0; j < 8; ++j) {
                float4 v = buf[j];            // (a_t, b_t, a_t+1, b_t+1)
                float4 o;
                o.x = sigz(__builtin_fmaf(c1x, v.x, c0x));
                o.y = sigz(__builtin_fmaf(c1y, v.y, c0y));
                o.z = sigz(__builtin_fmaf(c1x, v.z, c0x));
                o.w = sigz(__builtin_fmaf(c1y, v.w, c0y));
                sl[(h * 8 + j) * 32 + r] = o;   // same layout scan's ds_read expects
            }
        };
        auto flush = [&](int c) {     // st slot c&1 -> out, 256B coalesced runs
            const float* sl = st + ((c & 1) ? STSL : 0);
            const int col = lane & 31;
#pragma unroll
            for (int j = 0; j < 16; ++j) {
                int ro = 2 * j + (lane >> 5);
                float2 v = *(const float2*)&sl[ro * LDPAD + col * 2];
                out2[(size_t)(R0 + ro) * TLEN + (size_t)c * K + col] = v;
            }
        };

        // prologue: chunk 0 -> bufA -> produce; chunk 1 -> bufB (in flight)
#pragma unroll
        for (int j = 0; j < 8; ++j) bufA[j] = src[h * 8 + j];
        produce_reg(bufA, 0);
#pragma unroll
        for (int j = 0; j < 8; ++j) bufB[j] = src[16 + h * 8 + j];
        __syncthreads();                       // slot 0 ready for scan
        for (int c = 0; c < NC; ++c) {
            if ((c & 1) == 0) {
                if (c + 1 < NC) produce_reg(bufB, c + 1);   // chunk c+1 (odd)
                if (c + 2 < NC) {
#pragma unroll
                    for (int j = 0; j < 8; ++j)
                        bufA[j] = src[(c + 2) * 16 + h * 8 + j];
                }
            } else {
                if (c + 1 < NC) produce_reg(bufA, c + 1);   // chunk c+1 (even)
                if (c + 2 < NC) {
#pragma unroll
                    for (int j = 0; j < 8; ++j)
                        bufB[j] = src[(c + 2) * 16 + h * 8 + j];
                }
            }
            if (c >= 1) flush(c - 1);          // previous chunk's outputs
            __syncthreads();
        }
        flush(NC - 1);                         // epilogue: last chunk's outputs
    } else {
        // ---------------- scan wave ----------------
        // Lane pair (2r, 2r+1) owns row r: even lane = x, odd = y (r3 layout).
        const int r_  = lane >> 1;
        const int par = lane & 1;
        const int inB = par ? 6 : 2, sfB = par ? 22 : 18, t2B = par ? 10 : 14;
        const float ic  = 1.0f / prm[par];
        const float g1  = prm[sfB] * ic, P1 = g1 * prm[sfB + 3], Gn1 = -g1; // self
        const float g2  = prm[t2B] * ic, P2 = g2 * prm[t2B + 3], Gn2 = -g2; // cross
        const float gA  = prm[inB] * ic, PA = gA * prm[inB + 3], GnA = -gA; // input
        const float sdz = prm[sfB + 2];
        const float c1s = -sdz * L2E, c0s = sdz * prm[sfB + 1] * L2E;

        float x   = par ? 1.0f : 0.0f;
        float sig = sigz(__builtin_fmaf(c1s, x, c0s));
        float u   = __builtin_fmaf(-sig, sig, sig);   // sig*(1-sig)

        auto resync = [&]() {                         // exact sigma (off-chain)
            sig = sigz(__builtin_fmaf(c1s, x, c0s));
            u   = __builtin_fmaf(-sig, sig, sig);
        };

        auto step = [&](float sg, float* wp, int t) {
            float Av  = __builtin_fmaf(GnA, x, PA);
            float t1v = __builtin_fmaf(Gn1, x, P1);
            float t2v = __builtin_fmaf(Gn2, x, P2);
            float m   = sg * Av;                      // sgin precomputed by helper
            float b2  = __builtin_fmaf(sig, t1v, m);
            float sc  = lane_swap1(sig);              // partner's sigma
            float dx  = __builtin_fmaf(sc, t2v, b2);
            x = x + dx;
            wp[2 * t] = x;                            // ds_write_b32, imm offset
            float dz = sdz * dx;
            sig = __builtin_fmaf(u, dz, sig);         // deg-1 Taylor (was deg-2)
            u   = __builtin_fmaf(-sig, sig, sig);
        };

        __syncthreads();                       // sgbuf slot 0 ready
        for (int c = 0; c < NC; ++c) {
            const float4* lb = sgbuf + ((c & 1) ? SGSL : 0);
            float* wp = st + ((c & 1) ? STSL : 0) + r_ * LDPAD + par;
            float4 f0 = lb[r_];
            float4 f1 = lb[32 + r_];
#pragma unroll
            for (int tp = 0; tp < 16; ++tp) {
                float4 f = f0; f0 = f1;
                if (tp < 14) f1 = lb[(tp + 2) * 32 + r_];   // 2-pair lookahead
                step(par ? f.y : f.x, wp, 2 * tp);
                step(par ? f.w : f.z, wp, 2 * tp + 1);
                if (tp == 7) resync();                      // mid-chunk resync
            }
            resync();                                       // end-chunk resync
            __syncthreads();                   // hand slots to helper / get next
        }
    }
}

// ---------------------------------------------------------------------------
// Exact fallback for general params (proven path; 128-thr blocks cover all
// 8192 lanes).
// ---------------------------------------------------------------------------
struct LaneConst {
    float c1_in, c0_in, c1_sf, c0_sf, c1_ot, c0_ot;
    float gS_in, gS_cr, gS_sf, gP_in, gP_cr, gP_sf;
};

__device__ __forceinline__ float do_step_exact(float s, float pre_in, const LaneConst& k) {
    float sig_in = sigz(__builtin_fmaf(k.c1_in, pre_in, k.c0_in));
    float sig_sf = sigz(__builtin_fmaf(k.c1_sf, s, k.c0_sf));
    float sig_ot = sigz(__builtin_fmaf(k.c1_ot, s, k.c0_ot));
    float sig_cr = lane_swap1(sig_ot);
    float S = __builtin_fmaf(k.gS_in, sig_in, __builtin_fmaf(k.gS_cr, sig_cr, k.gS_sf * sig_sf));
    float P = __builtin_fmaf(k.gP_in, sig_in, __builtin_fmaf(k.gP_cr, sig_cr, k.gP_sf * sig_sf));
    return s + __builtin_fmaf(S, -s, P);
}

__device__ void run_exact(const float* __restrict__ inp, const float* __restrict__ prm,
                          float* __restrict__ out) {
    const int tid = blockIdx.x * 128 + threadIdx.x;
    const int row = tid >> 1;
    if (row >= NROWS) return;
    const int par = tid & 1;
    const float L2E = 1.4426950408889634f;
    const int inB = par ? 6 : 2, sfB = par ? 22 : 18, otB = par ? 14 : 10, crB = par ? 10 : 14;
    const float invc = 1.0f / prm[par];
    LaneConst k;
    float sd = prm[inB + 2], mn = prm[inB + 1];
    k.c1_in = -sd * L2E; k.c0_in = sd * mn * L2E;
    sd = prm[sfB + 2]; mn = prm[sfB + 1];
    k.c1_sf = -sd * L2E; k.c0_sf = sd * mn * L2E;
    sd = prm[otB + 2]; mn = prm[otB + 1];
    k.c1_ot = -sd * L2E; k.c0_ot = sd * mn * L2E;
    k.gS_in = prm[inB] * invc; k.gP_in = k.gS_in * prm[inB + 3];
    k.gS_sf = prm[sfB] * invc; k.gP_sf = k.gS_sf * prm[sfB + 3];
    k.gS_cr = prm[crB] * invc; k.gP_cr = k.gS_cr * prm[crB + 3];

    const float4* __restrict__ src = (const float4*)inp + (size_t)row * (TLEN / 2);
    float* __restrict__ dst = out + (size_t)row * (TLEN * 2) + par;
    float s = par ? 1.0f : 0.0f;

    float4 cur[UN], nxt[UN];
#pragma unroll
    for (int j = 0; j < UN; ++j) cur[j] = src[j];
    const int NIT = TLEN / (2 * UN);
    for (int it = 0; it < NIT; ++it) {
        if (it + 1 < NIT) {
#pragma unroll
            for (int j = 0; j < UN; ++j) nxt[j] = src[(it + 1) * UN + j];
        }
        float* dptr = dst + it * (UN * 4);
#pragma unroll
        for (int j = 0; j < UN; ++j) {
            float4 f = cur[j];
            s = do_step_exact(s, par ? f.y : f.x, k);
            dptr[j * 4] = s;
            s = do_step_exact(s, par ? f.w : f.z, k);
            dptr[j * 4 + 2] = s;
        }
#pragma unroll
        for (int j = 0; j < UN; ++j) cur[j] = nxt[j];
    }
}

__global__ __launch_bounds__(128, 1)
void memcell_scan(const float* __restrict__ inp, const float* __restrict__ prm,
                  float* __restrict__ out) {
    __shared__ float4 sgbuf[2 * SGSL];   // 16 KB sgin double-buffer
    __shared__ float  st[2 * STSL];      // 16.9 KB output staging double-buffer

    // Fast-path guard:
    //  - shared (mean,std) between self & cross state dirs (xx==xy, yy==yx)
    //  - g >= 0, caps > 0         -> states stay in hull{s0, pots}
    //  - sum(g/cap) <= 0.25       -> no overshoot
    //  - wb = std*max|dx| <= 0.02 -> deg-1 sigma-Taylor valid
    //    (exact resync every 16 steps bounds drift to ~1e-4)
    //  - |z| <= 20                -> sigz well-conditioned
    const bool shared = (prm[11] == prm[19]) && (prm[12] == prm[20]) &&
                        (prm[15] == prm[23]) && (prm[16] == prm[24]);
    const float capx = prm[0], capy = prm[1];
    const bool gpos = prm[2] >= 0.f && prm[6] >= 0.f && prm[10] >= 0.f &&
                      prm[14] >= 0.f && prm[18] >= 0.f && prm[22] >= 0.f &&
                      capx > 0.f && capy > 0.f;
    const float sx = (prm[2] + prm[14] + prm[18]) / capx;
    const float sy = (prm[6] + prm[10] + prm[22]) / capy;
    const float lox = fminf(0.f, fminf(prm[5], fminf(prm[17], prm[21])));
    const float hix = fmaxf(0.f, fmaxf(prm[5], fmaxf(prm[17], prm[21])));
    const float loy = fminf(1.f, fminf(prm[9], fminf(prm[13], prm[25])));
    const float hiy = fmaxf(1.f, fmaxf(prm[9], fmaxf(prm[13], prm[25])));
    const float wbx = prm[20] * sx * (hix - lox), wby = prm[24] * sy * (hiy - loy);
    const float zmx = prm[20] * fmaxf(fabsf(lox - prm[19]), fabsf(hix - prm[19]));
    const float zmy = prm[24] * fmaxf(fabsf(loy - prm[23]), fabsf(hiy - prm[23]));
    const bool fast = shared && gpos && sx <= 0.25f && sy <= 0.25f &&
                      wbx <= 0.02f && wby <= 0.02f && zmx <= 20.f && zmy <= 20.f;
    if (fast) {
        run_fast(inp, prm, out, sgbuf, st);
    } else {
        run_exact(inp, prm, out);
    }
}

extern "C" void kernel_launch(void* const* d_in, const int* in_sizes, int n_in,
                              void* d_out, int out_size, void* d_ws, size_t ws_size,
                              hipStream_t stream) {
    (void)in_sizes; (void)n_in; (void)d_ws; (void)ws_size; (void)out_size;
    const float* inp = (const float*)d_in[0];
    const float* prm = (const float*)d_in[1];
    float* out = (float*)d_out;
    memcell_scan<<<dim3(NROWS / RPB), dim3(128), 0, stream>>>(inp, prm, out);
}